// Round 15
// baseline (83.806 us; speedup 1.0000x reference)
//
#include <hip/hip_runtime.h>

#define NTHREADS 256

typedef __attribute__((ext_vector_type(8))) short bf16x8;
typedef __attribute__((ext_vector_type(4))) short s16x4;
typedef __attribute__((ext_vector_type(4))) float f32x4;

constexpr int Bx = 4, Cx = 256, Tx = 2048, Hx = 4, Gx = 8, HDx = 64, CGx = 32;
constexpr float EPSx = 1e-5f;
constexpr int NSPLIT = 8, ZSHIFT = 3;
// HD^-0.5 * log2(e): folded into Q so softmax uses exp2 directly
constexpr float QSCALE = 0.125f * 1.44269504088896340736f;
// Fixed softmax shift (log2 units): |score*log2e| << 16 for this data; 2^-SHIFT
// cancels in O = PV/l, LSE = SHIFT + log2(l) keeps the split-KV merge exact.
constexpr float SHIFT = 16.0f;

__device__ __forceinline__ float bf2f(short s) {
  union { unsigned u; float f; } c;
  c.u = ((unsigned)(unsigned short)s) << 16;
  return c.f;
}
__device__ __forceinline__ short f2bf(float f) {
  union { float f; unsigned u; } c; c.f = f;
  unsigned r = c.u + 0x7fffu + ((c.u >> 16) & 1u);
  return (short)(r >> 16);
}
__device__ __forceinline__ unsigned cvtpk(float lo, float hi) {
  unsigned r;
  asm("v_cvt_pk_bf16_f32 %0, %1, %2" : "=v"(r) : "v"(lo), "v"(hi));
  return r;
}
__device__ __forceinline__ float fexp2(float x) { return __builtin_amdgcn_exp2f(x); }
__device__ __forceinline__ void gload16(const void* g, void* l) {
  __builtin_amdgcn_global_load_lds((const __attribute__((address_space(1))) void*)g,
                                   (__attribute__((address_space(3))) void*)l, 16, 0, 0);
}

// ---- 1. fused: blocks 0..255 = GroupNorm partial sums (B*G*8); blocks 256..511 = weight cvt x4 ----
__global__ void k_pre(const float* __restrict__ x, float2* __restrict__ part,
                      const float* __restrict__ wq, const float* __restrict__ wo,
                      short* __restrict__ oq, short* __restrict__ oo) {
  if (blockIdx.x < Bx * Gx * 8) {   // 256 slabs of 8192 floats
    int blk = blockIdx.x;
    const f32x4* xv = (const f32x4*)(x + (size_t)blk * 8192);
    float s = 0.f, ss = 0.f;
    for (int i = threadIdx.x; i < 2048; i += NTHREADS) {
      f32x4 v = xv[i];
      s += v[0] + v[1] + v[2] + v[3];
      ss += v[0]*v[0] + v[1]*v[1] + v[2]*v[2] + v[3]*v[3];
    }
    #pragma unroll
    for (int m = 32; m >= 1; m >>= 1) { s += __shfl_xor(s, m, 64); ss += __shfl_xor(ss, m, 64); }
    __shared__ float ls[4], lss[4];
    int wid = threadIdx.x >> 6;
    if ((threadIdx.x & 63) == 0) { ls[wid] = s; lss[wid] = ss; }
    __syncthreads();
    if (threadIdx.x == 0) {
      float S = 0.f, SS = 0.f;
      #pragma unroll
      for (int w = 0; w < 4; w++) { S += ls[w]; SS += lss[w]; }
      part[blk] = make_float2(S, SS);
    }
  } else {
    int gid = (blockIdx.x - Bx * Gx * 8) * NTHREADS + threadIdx.x;
    int e = gid * 4;
    if (e < 3 * Cx * Cx) {
      f32x4 v = *(const f32x4*)(wq + e);
      s16x4 o = {f2bf(v[0]), f2bf(v[1]), f2bf(v[2]), f2bf(v[3])};
      *(s16x4*)(oq + e) = o;
    } else {
      int e2 = e - 3 * Cx * Cx;
      if (e2 < Cx * Cx) {
        f32x4 v = *(const f32x4*)(wo + e2);
        s16x4 o = {f2bf(v[0]), f2bf(v[1]), f2bf(v[2]), f2bf(v[3])};
        *(s16x4*)(oo + e2) = o;
      }
    }
  }
}

// ---- 3. normalize + affine + transpose x[B,C,T] -> h[B,T,C] bf16; 32c x 128t tiles ----
__global__ void k_gn_apply(const float* __restrict__ x, const float* __restrict__ gw,
                           const float* __restrict__ gb, const float2* __restrict__ part,
                           short* __restrict__ h) {
  int b = blockIdx.z, c0 = blockIdx.y * 32, t0 = blockIdx.x * 128;
  int g = c0 >> 5;  // CG = 32: one group per c-block
  float S = 0.f, SS = 0.f;
  #pragma unroll
  for (int j = 0; j < 8; j++) { float2 p = part[(b * Gx + g) * 8 + j]; S += p.x; SS += p.y; }
  float inv = 1.f / (float)(CGx * Tx);
  float mu = S * inv;
  float rs = rsqrtf(SS * inv - mu * mu + EPSx);

  __shared__ float tile[32][129];
  int tx = threadIdx.x & 31, ty = threadIdx.x >> 5;   // tx: t-chunk of 4, ty: c-row of 8
  #pragma unroll
  for (int i = 0; i < 4; i++) {
    int cl = ty + i * 8;
    int c = c0 + cl;
    float wv = gw[c] * rs, bv = gb[c] - mu * rs * gw[c];
    f32x4 v = *(const f32x4*)(x + ((size_t)b * Cx + c) * Tx + t0 + tx * 4);
    #pragma unroll
    for (int k = 0; k < 4; k++) tile[cl][tx * 4 + k] = v[k] * wv + bv;
  }
  __syncthreads();
  #pragma unroll
  for (int i = 0; i < 16; i++) {
    int tl = ty + i * 8;
    h[((size_t)b * Tx + t0 + tl) * Cx + c0 + tx] = f2bf(tile[tx][tl]);
  }
}

// ---- 4. QKV GEMM, 2 m-sets/wave (32 rows): writes Q (pre-scaled), K, V^T (sigma-permuted).
// grid (64, 12): block tile 128m x 64n; wave = 32m x 64n; per k-step 2 A + 4 B loads / 8 MFMAs.
__global__ __launch_bounds__(256) void k_gemm_qkv(
    const short* __restrict__ A, const short* __restrict__ Bt,
    const float* __restrict__ bias, short* __restrict__ qg,
    short* __restrict__ kgo, short* __restrict__ vtg) {
  constexpr int K = 256;
  __shared__ short tlt[64][130];  // V staging [hd][t-permuted, 128 wide], stride 130
  int wid = threadIdx.x >> 6, lane = threadIdx.x & 63;
  int m0 = blockIdx.x * 128 + wid * 16;   // m-set 0; m-set 1 = m0 + 64
  int n0 = blockIdx.y * 64;
  int row = lane & 15, kg = lane >> 4;
  f32x4 acc[2][4] = {};
  const short* Ap0 = A + (size_t)(m0 + row) * K + kg * 8;
  const short* Ap1 = Ap0 + (size_t)64 * K;
  const short* Bp0 = Bt + (size_t)(n0 + row) * K + kg * 8;
  #pragma unroll
  for (int k = 0; k < K; k += 32) {
    bf16x8 af0 = *(const bf16x8*)(Ap0 + k);
    bf16x8 af1 = *(const bf16x8*)(Ap1 + k);
    #pragma unroll
    for (int nt = 0; nt < 4; nt++) {
      bf16x8 bf = *(const bf16x8*)(Bp0 + (size_t)nt * 16 * K + k);
      acc[0][nt] = __builtin_amdgcn_mfma_f32_16x16x32_bf16(af0, bf, acc[0][nt], 0, 0, 0);
      acc[1][nt] = __builtin_amdgcn_mfma_f32_16x16x32_bf16(af1, bf, acc[1][nt], 0, 0, 0);
    }
  }
  int sec = n0 >> 8, hh = (n0 >> 6) & 3;
  int bB = (blockIdx.x * 128) >> 11, t0 = (blockIdx.x * 128) & (Tx - 1);
  if (sec < 2) {
    #pragma unroll
    for (int ms = 0; ms < 2; ms++)
      #pragma unroll
      for (int nt = 0; nt < 4; nt++)
        #pragma unroll
        for (int r = 0; r < 4; r++) {
          int m = m0 + ms * 64 + kg * 4 + r;
          int n = n0 + nt * 16 + row;
          int b = m >> 11, t = m & (Tx - 1), hd = n & 63;
          float v = acc[ms][nt][r] + bias[n];
          if (sec == 0)
            qg[(((size_t)b * Hx + hh) * Tx + t) * 64 + hd] = f2bf(v * QSCALE);
          else
            kgo[(((size_t)b * Hx + hh) * Tx + t) * 64 + hd] = f2bf(v);
        }
  } else {
    // V: stage sigma-permuted transposed tile (two 64-t chunks), write V^T rows coalesced.
    // within each 64-chunk: tau = wid*16 + kg*4 + r -> p = (wid>>1)*32 + kg*8 + (wid&1)*4 + r
    int tlb = (wid >> 1) * 32 + kg * 8 + (wid & 1) * 4;
    #pragma unroll
    for (int ms = 0; ms < 2; ms++) {
      int tl = ms * 64 + tlb;
      #pragma unroll
      for (int nt = 0; nt < 4; nt++) {
        int n = n0 + nt * 16 + row;
        float bn = bias[n];
        int hd = nt * 16 + row;
        *(unsigned*)&tlt[hd][tl]     = cvtpk(acc[ms][nt][0] + bn, acc[ms][nt][1] + bn);
        *(unsigned*)&tlt[hd][tl + 2] = cvtpk(acc[ms][nt][2] + bn, acc[ms][nt][3] + bn);
      }
    }
    __syncthreads();
    int hd = threadIdx.x >> 2, tch = (threadIdx.x & 3) * 32;
    short* vr = vtg + (((size_t)bB * Hx + hh) * 64 + hd) * Tx + t0 + tch;
    #pragma unroll
    for (int j = 0; j < 32; j += 2) *(unsigned*)(vr + j) = *(unsigned*)&tlt[hd][tch + j];
  }
}

// ---- 5. flash attention, split-KV x8, 4 waves x 32q = 128 q/block, fixed-shift softmax ----
// grid 2048: g = bid & 127: sp = g & 7, bh = g >> 3, x = bid >> 7 (same-XCD groups).
#define KVB 64
__global__ __launch_bounds__(256) void k_attn(const short* __restrict__ qg,
                                              const short* __restrict__ kgl,
                                              const short* __restrict__ vtg,
                                              short* __restrict__ po,
                                              float* __restrict__ ps) {
  // LDS (shorts): K dbuf 2x[64 kv][64 d] @0, V^T dbuf 2x[64 d][64 kv] @8192
  __shared__ short lds[16384];
  const int bid = blockIdx.x;
  const int g = bid & (16 * NSPLIT - 1);
  const int sp = g & (NSPLIT - 1);
  const int bh = g >> ZSHIFT;
  constexpr int kvlen = Tx / NSPLIT;
  const int kvbase = sp * kvlen;
  const int wid = threadIdx.x >> 6, lane = threadIdx.x & 63;
  const int row = lane & 15, kg4 = lane >> 4;
  const int q0 = (bid >> (4 + ZSHIFT)) * 128 + wid * 32;
  const short* qbase = qg + (size_t)bh * Tx * 64;
  const short* kbase = kgl + (size_t)bh * Tx * 64;
  const short* vbase = vtg + (size_t)bh * 64 * Tx;

  bf16x8 qf[2][2];
  #pragma unroll
  for (int qs = 0; qs < 2; ++qs)
    #pragma unroll
    for (int c = 0; c < 2; ++c)
      qf[qs][c] = *(const bf16x8*)(qbase + (size_t)(q0 + qs * 16 + row) * 64 + c * 32 + kg4 * 8);

  // hoisted staging addressing: wave-uniform LDS dest, pre-swizzled global src.
  // LDS[r][slot s] = SRC[r][s ^ (r&7)] (16B slots, 8 per 128B row)
  const int idx0 = wid * 64 + lane, idx1 = idx0 + 256;
  const int rr0 = idx0 >> 3, sl0 = (idx0 & 7) ^ (rr0 & 7);
  const int rr1 = idx1 >> 3, sl1 = (idx1 & 7) ^ (rr1 & 7);
  const short* ks0 = kbase + (size_t)(kvbase + rr0) * 64 + sl0 * 8;
  const short* ks1 = kbase + (size_t)(kvbase + rr1) * 64 + sl1 * 8;
  const short* vs0 = vbase + (size_t)rr0 * Tx + kvbase + sl0 * 8;
  const short* vs1 = vbase + (size_t)rr1 * Tx + kvbase + sl1 * 8;
  short* const kd0 = lds + wid * 512;
  short* const kd1 = lds + wid * 512 + 2048;
  short* const vd0 = lds + 8192 + wid * 512;
  short* const vd1 = lds + 8192 + wid * 512 + 2048;
  auto stage = [&](int sbuf, int itn) {
    const int ko = itn * 4096, vo = itn * 64, so = sbuf * 4096;
    gload16(ks0 + ko, kd0 + so);
    gload16(ks1 + ko, kd1 + so);
    gload16(vs0 + vo, vd0 + so);
    gload16(vs1 + vo, vd1 + so);
  };

  const int swz = row & 7;
  const int kc0 = (kg4 ^ swz) * 8;         // b128 frag offsets, shared by K and sigma'd V
  const int kc1 = ((4 + kg4) ^ swz) * 8;
  int vro[4];
  #pragma unroll
  for (int nt = 0; nt < 4; ++nt) vro[nt] = (nt * 16 + row) * 64;

  float l0 = 0.f, l1 = 0.f;
  f32x4 oa0[4] = {}, oa1[4] = {};
  constexpr int nit = kvlen / KVB;

  stage(0, 0);
  #pragma unroll 2
  for (int it = 0; it < nit; ++it) {
    const int cur = it & 1;
    if (it + 1 < nit) {
      stage(cur ^ 1, it + 1);
      asm volatile("s_waitcnt vmcnt(4)" ::: "memory");
    } else {
      asm volatile("s_waitcnt vmcnt(0)" ::: "memory");
    }
    __builtin_amdgcn_s_barrier();

    const short* Kb = lds + (cur << 12);
    const short* Vb = lds + 8192 + (cur << 12);

    // QK^T (C seeded -SHIFT) -> exp2 -> pack per t-tile; 2 q-sets
    union U { unsigned u[4]; bf16x8 v; };
    U a00, a01, a10, a11;
    float rs0 = 0.f, rs1 = 0.f;
    __builtin_amdgcn_s_setprio(1);
    #pragma unroll
    for (int t = 0; t < 4; ++t) {
      const short* kr = Kb + vro[t];
      bf16x8 kf0 = *(const bf16x8*)(kr + kc0);
      bf16x8 kf1 = *(const bf16x8*)(kr + kc1);
      f32x4 x0 = {-SHIFT, -SHIFT, -SHIFT, -SHIFT};
      f32x4 x1 = {-SHIFT, -SHIFT, -SHIFT, -SHIFT};
      x0 = __builtin_amdgcn_mfma_f32_16x16x32_bf16(kf0, qf[0][0], x0, 0, 0, 0);
      x0 = __builtin_amdgcn_mfma_f32_16x16x32_bf16(kf1, qf[0][1], x0, 0, 0, 0);
      x1 = __builtin_amdgcn_mfma_f32_16x16x32_bf16(kf0, qf[1][0], x1, 0, 0, 0);
      x1 = __builtin_amdgcn_mfma_f32_16x16x32_bf16(kf1, qf[1][1], x1, 0, 0, 0);
      float e0 = fexp2(x0[0]), e1 = fexp2(x0[1]), e2 = fexp2(x0[2]), e3 = fexp2(x0[3]);
      rs0 += (e0 + e1) + (e2 + e3);
      unsigned w0 = cvtpk(e0, e1), w1 = cvtpk(e2, e3);
      float f0 = fexp2(x1[0]), f1 = fexp2(x1[1]), f2 = fexp2(x1[2]), f3 = fexp2(x1[3]);
      rs1 += (f0 + f1) + (f2 + f3);
      unsigned y0 = cvtpk(f0, f1), y1 = cvtpk(f2, f3);
      if (t < 2) {
        a00.u[t * 2] = w0; a00.u[t * 2 + 1] = w1;
        a10.u[t * 2] = y0; a10.u[t * 2 + 1] = y1;
      } else {
        a01.u[(t - 2) * 2] = w0; a01.u[(t - 2) * 2 + 1] = w1;
        a11.u[(t - 2) * 2] = y0; a11.u[(t - 2) * 2 + 1] = y1;
      }
    }
    __builtin_amdgcn_s_setprio(0);
    l0 += rs0; l1 += rs1;

    // O += P V : A-frag k-slot j -> kv = kc*32 + (j>>2)*16 + kg4*4 + (j&3);
    // sigma'd V makes the matching B-frag a single b128 at kc0/kc1.
    __builtin_amdgcn_s_setprio(1);
    #pragma unroll
    for (int nt = 0; nt < 4; ++nt) {
      const short* vr = Vb + vro[nt];
      bf16x8 vf0 = *(const bf16x8*)(vr + kc0);
      bf16x8 vf1 = *(const bf16x8*)(vr + kc1);
      oa0[nt] = __builtin_amdgcn_mfma_f32_16x16x32_bf16(a00.v, vf0, oa0[nt], 0, 0, 0);
      oa1[nt] = __builtin_amdgcn_mfma_f32_16x16x32_bf16(a10.v, vf0, oa1[nt], 0, 0, 0);
      oa0[nt] = __builtin_amdgcn_mfma_f32_16x16x32_bf16(a01.v, vf1, oa0[nt], 0, 0, 0);
      oa1[nt] = __builtin_amdgcn_mfma_f32_16x16x32_bf16(a11.v, vf1, oa1[nt], 0, 0, 0);
    }
    __builtin_amdgcn_s_setprio(0);
    __builtin_amdgcn_s_barrier();
  }

  // epilogue: reduce l across kv-groups once, write partials
  l0 += __shfl_xor(l0, 16, 64); l0 += __shfl_xor(l0, 32, 64);
  l1 += __shfl_xor(l1, 16, 64); l1 += __shfl_xor(l1, 32, 64);
  float li0[4], li1[4];
  #pragma unroll
  for (int r = 0; r < 4; ++r) {
    li0[r] = 1.f / __shfl(l0, kg4 * 4 + r, 64);
    li1[r] = 1.f / __shfl(l1, kg4 * 4 + r, 64);
  }
  short* pob = po + (((size_t)sp * 16 + bh) * Tx) * 64;
  #pragma unroll
  for (int nt = 0; nt < 4; ++nt)
    #pragma unroll
    for (int r = 0; r < 4; ++r) {
      int t = q0 + kg4 * 4 + r;
      pob[(size_t)t * 64 + nt * 16 + row] = f2bf(oa0[nt][r] * li0[r]);
      pob[(size_t)(t + 16) * 64 + nt * 16 + row] = f2bf(oa1[nt][r] * li1[r]);
    }
  if (kg4 == 0) {
    float* psb = ps + ((size_t)sp * 16 + bh) * Tx;
    psb[q0 + row] = SHIFT + __log2f(l0);
    psb[q0 + 16 + row] = SHIFT + __log2f(l1);
  }
}

// ---- 6. fused merge + proj GEMM + bias + residual (no aout round-trip) ----
__global__ __launch_bounds__(256) void k_proj(
    const short* __restrict__ po, const float* __restrict__ ps,
    const short* __restrict__ Bt, const float* __restrict__ bias,
    const float* __restrict__ x, float* __restrict__ out) {
  __shared__ float tlt[128][65];
  const int wid = threadIdx.x >> 6, lane = threadIdx.x & 63;
  const int row = lane & 15, kg = lane >> 4;
  const int mb = blockIdx.x * 64;
  const int b = mb >> 11, t0 = mb & (Tx - 1);
  const int n0 = blockIdx.y * 128;
  const int t = t0 + wid * 16 + row;   // this lane's A-row (time index)

  // per-head LSE merge weights for this t
  float wgt[4][NSPLIT], dinv[4];
  #pragma unroll
  for (int h = 0; h < 4; ++h) {
    float s0[NSPLIT], mx = -1e30f;
    #pragma unroll
    for (int sp = 0; sp < NSPLIT; ++sp) {
      s0[sp] = ps[((size_t)sp * 16 + b * 4 + h) * Tx + t];
      mx = fmaxf(mx, s0[sp]);
    }
    float d = 0.f;
    #pragma unroll
    for (int sp = 0; sp < NSPLIT; ++sp) { wgt[h][sp] = fexp2(s0[sp] - mx); d += wgt[h][sp]; }
    dinv[h] = 1.f / d;
  }

  // accumulate weighted partials into the lane's 64 A-elements
  float a[8][8] = {};
  #pragma unroll
  for (int sp = 0; sp < NSPLIT; ++sp) {
    #pragma unroll
    for (int j = 0; j < 8; ++j) {
      int c = j * 32 + kg * 8;
      int h = c >> 6, d0 = c & 63;
      const short* q = po + (((size_t)sp * 16 + b * 4 + h) * Tx + t) * 64 + d0;
      bf16x8 v = *(const bf16x8*)q;
      float wv = wgt[h][sp];
      #pragma unroll
      for (int e = 0; e < 8; ++e) a[j][e] += wv * bf2f(v[e]);
    }
  }
  // normalize + pack A-frags
  bf16x8 af[8];
  #pragma unroll
  for (int j = 0; j < 8; ++j) {
    float dv = dinv[(j * 32 + kg * 8) >> 6];
    union { unsigned u[4]; bf16x8 v; } p;
    #pragma unroll
    for (int e = 0; e < 4; ++e) p.u[e] = cvtpk(a[j][2 * e] * dv, a[j][2 * e + 1] * dv);
    af[j] = p.v;
  }

  // GEMM: A in regs, B from global (L2-hot 128 KB)
  f32x4 acc[8] = {};
  #pragma unroll
  for (int j = 0; j < 8; ++j) {
    #pragma unroll
    for (int nt = 0; nt < 8; ++nt) {
      bf16x8 bf = *(const bf16x8*)(Bt + (size_t)(n0 + nt * 16 + row) * 256 + j * 32 + kg * 8);
      acc[nt] = __builtin_amdgcn_mfma_f32_16x16x32_bf16(af[j], bf, acc[nt], 0, 0, 0);
    }
  }

  // transposed epilogue with residual
  #pragma unroll
  for (int nt = 0; nt < 8; ++nt) {
    float bn = bias[n0 + nt * 16 + row];
    #pragma unroll
    for (int r = 0; r < 4; ++r)
      tlt[nt * 16 + row][wid * 16 + kg * 4 + r] = acc[nt][r] + bn;
  }
  __syncthreads();
  int cl = threadIdx.x >> 1, tch = (threadIdx.x & 1) * 32;
  int c = n0 + cl;
  const float* xr = x + ((size_t)b * Cx + c) * Tx + t0 + tch;
  float* orow = out + ((size_t)b * Cx + c) * Tx + t0 + tch;
  #pragma unroll
  for (int j = 0; j < 32; j += 4) {
    f32x4 xv = *(const f32x4*)(xr + j);
    f32x4 v;
    #pragma unroll
    for (int jj = 0; jj < 4; ++jj) v[jj] = xv[jj] + tlt[cl][tch + j + jj];
    *(f32x4*)(orow + j) = v;
  }
}

extern "C" void kernel_launch(void* const* d_in, const int* in_sizes, int n_in,
                              void* d_out, int out_size, void* d_ws, size_t ws_size,
                              hipStream_t stream) {
  const float* x     = (const float*)d_in[0];
  const float* gn_w  = (const float*)d_in[1];
  const float* gn_b  = (const float*)d_in[2];
  const float* w_qkv = (const float*)d_in[3];
  const float* b_qkv = (const float*)d_in[4];
  const float* w_out = (const float*)d_in[5];
  const float* b_out = (const float*)d_in[6];
  float* out = (float*)d_out;

  char* ws = (char*)d_ws;
  size_t off = 0;
  auto alloc = [&](size_t bytes) -> void* {
    void* p = ws + off;
    off += bytes;
    off = (off + 255) & ~(size_t)255;
    return p;
  };
  float2* part  = (float2*)alloc((size_t)Bx * Gx * 8 * sizeof(float2));
  short* h      = (short*)alloc((size_t)Bx * Tx * Cx * 2);
  short* wqkvb  = (short*)alloc((size_t)3 * Cx * Cx * 2);
  short* woutb  = (short*)alloc((size_t)Cx * Cx * 2);
  short* qg     = (short*)alloc((size_t)Bx * Hx * Tx * 64 * 2);
  short* kgo    = (short*)alloc((size_t)Bx * Hx * Tx * 64 * 2);
  short* vtg    = (short*)alloc((size_t)Bx * Hx * 64 * Tx * 2);
  short* po     = (short*)alloc((size_t)NSPLIT * 16 * Tx * 64 * 2);
  float* ps     = (float*)alloc((size_t)NSPLIT * 16 * Tx * sizeof(float));

  k_pre<<<Bx * Gx * 8 + (Cx * Cx + NTHREADS - 1) / NTHREADS, NTHREADS, 0, stream>>>(
      x, part, w_qkv, w_out, wqkvb, woutb);
  k_gn_apply<<<dim3(Tx / 128, Cx / 32, Bx), NTHREADS, 0, stream>>>(x, gn_w, gn_b, part, h);
  k_gemm_qkv<<<dim3(Bx * Tx / 128, 3 * Cx / 64), NTHREADS, 0, stream>>>(h, wqkvb, b_qkv, qg, kgo, vtg);
  k_attn<<<16 * 16 * NSPLIT, 256, 0, stream>>>(qg, kgo, vtg, po, ps);
  k_proj<<<dim3(Bx * Tx / 64, 2), NTHREADS, 0, stream>>>(po, ps, woutb, b_out, x, out);
}

// Round 16
// 76.397 us; speedup vs baseline: 1.0970x; 1.0970x over previous
//
#include <hip/hip_runtime.h>

#define NTHREADS 256

typedef __attribute__((ext_vector_type(8))) short bf16x8;
typedef __attribute__((ext_vector_type(4))) short s16x4;
typedef __attribute__((ext_vector_type(4))) float f32x4;

constexpr int Bx = 4, Cx = 256, Tx = 2048, Hx = 4, Gx = 8, HDx = 64, CGx = 32;
constexpr float EPSx = 1e-5f;
constexpr int NSPLIT = 4, ZSHIFT = 2;
// HD^-0.5 * log2(e): folded into Q so softmax uses exp2 directly
constexpr float QSCALE = 0.125f * 1.44269504088896340736f;
// Fixed softmax shift (log2 units): |score*log2e| << 16 for this data; 2^-SHIFT
// cancels in O = PV/l, LSE = SHIFT + log2(l) keeps the split-KV merge exact.
constexpr float SHIFT = 16.0f;

__device__ __forceinline__ float bf2f(short s) {
  union { unsigned u; float f; } c;
  c.u = ((unsigned)(unsigned short)s) << 16;
  return c.f;
}
__device__ __forceinline__ short f2bf(float f) {
  union { float f; unsigned u; } c; c.f = f;
  unsigned r = c.u + 0x7fffu + ((c.u >> 16) & 1u);
  return (short)(r >> 16);
}
__device__ __forceinline__ unsigned cvtpk(float lo, float hi) {
  unsigned r;
  asm("v_cvt_pk_bf16_f32 %0, %1, %2" : "=v"(r) : "v"(lo), "v"(hi));
  return r;
}
__device__ __forceinline__ float fexp2(float x) { return __builtin_amdgcn_exp2f(x); }
__device__ __forceinline__ void gload16(const void* g, void* l) {
  __builtin_amdgcn_global_load_lds((const __attribute__((address_space(1))) void*)g,
                                   (__attribute__((address_space(3))) void*)l, 16, 0, 0);
}

// ---- 1. fused: blocks 0..255 = GroupNorm partial sums (B*G*8); blocks 256..511 = weight cvt x4 ----
__global__ void k_pre(const float* __restrict__ x, float2* __restrict__ part,
                      const float* __restrict__ wq, const float* __restrict__ wo,
                      short* __restrict__ oq, short* __restrict__ oo) {
  if (blockIdx.x < Bx * Gx * 8) {   // 256 slabs of 8192 floats
    int blk = blockIdx.x;
    const f32x4* xv = (const f32x4*)(x + (size_t)blk * 8192);
    float s = 0.f, ss = 0.f;
    for (int i = threadIdx.x; i < 2048; i += NTHREADS) {
      f32x4 v = xv[i];
      s += v[0] + v[1] + v[2] + v[3];
      ss += v[0]*v[0] + v[1]*v[1] + v[2]*v[2] + v[3]*v[3];
    }
    #pragma unroll
    for (int m = 32; m >= 1; m >>= 1) { s += __shfl_xor(s, m, 64); ss += __shfl_xor(ss, m, 64); }
    __shared__ float ls[4], lss[4];
    int wid = threadIdx.x >> 6;
    if ((threadIdx.x & 63) == 0) { ls[wid] = s; lss[wid] = ss; }
    __syncthreads();
    if (threadIdx.x == 0) {
      float S = 0.f, SS = 0.f;
      #pragma unroll
      for (int w = 0; w < 4; w++) { S += ls[w]; SS += lss[w]; }
      part[blk] = make_float2(S, SS);
    }
  } else {
    int gid = (blockIdx.x - Bx * Gx * 8) * NTHREADS + threadIdx.x;
    int e = gid * 4;
    if (e < 3 * Cx * Cx) {
      f32x4 v = *(const f32x4*)(wq + e);
      s16x4 o = {f2bf(v[0]), f2bf(v[1]), f2bf(v[2]), f2bf(v[3])};
      *(s16x4*)(oq + e) = o;
    } else {
      int e2 = e - 3 * Cx * Cx;
      if (e2 < Cx * Cx) {
        f32x4 v = *(const f32x4*)(wo + e2);
        s16x4 o = {f2bf(v[0]), f2bf(v[1]), f2bf(v[2]), f2bf(v[3])};
        *(s16x4*)(oo + e2) = o;
      }
    }
  }
}

// ---- 3. normalize + affine + transpose x[B,C,T] -> h[B,T,C] bf16; 32c x 128t tiles ----
__global__ void k_gn_apply(const float* __restrict__ x, const float* __restrict__ gw,
                           const float* __restrict__ gb, const float2* __restrict__ part,
                           short* __restrict__ h) {
  int b = blockIdx.z, c0 = blockIdx.y * 32, t0 = blockIdx.x * 128;
  int g = c0 >> 5;  // CG = 32: one group per c-block
  float S = 0.f, SS = 0.f;
  #pragma unroll
  for (int j = 0; j < 8; j++) { float2 p = part[(b * Gx + g) * 8 + j]; S += p.x; SS += p.y; }
  float inv = 1.f / (float)(CGx * Tx);
  float mu = S * inv;
  float rs = rsqrtf(SS * inv - mu * mu + EPSx);

  __shared__ float tile[32][129];
  int tx = threadIdx.x & 31, ty = threadIdx.x >> 5;   // tx: t-chunk of 4, ty: c-row of 8
  #pragma unroll
  for (int i = 0; i < 4; i++) {
    int cl = ty + i * 8;
    int c = c0 + cl;
    float wv = gw[c] * rs, bv = gb[c] - mu * rs * gw[c];
    f32x4 v = *(const f32x4*)(x + ((size_t)b * Cx + c) * Tx + t0 + tx * 4);
    #pragma unroll
    for (int k = 0; k < 4; k++) tile[cl][tx * 4 + k] = v[k] * wv + bv;
  }
  __syncthreads();
  #pragma unroll
  for (int i = 0; i < 16; i++) {
    int tl = ty + i * 8;
    h[((size_t)b * Tx + t0 + tl) * Cx + c0 + tx] = f2bf(tile[tx][tl]);
  }
}

// ---- 4. QKV GEMM, 2 m-sets/wave (32 rows): writes Q (pre-scaled), K, V^T (sigma-permuted).
// grid (64, 12): block tile 128m x 64n; wave = 32m x 64n; per k-step 2 A + 4 B loads / 8 MFMAs.
__global__ __launch_bounds__(256) void k_gemm_qkv(
    const short* __restrict__ A, const short* __restrict__ Bt,
    const float* __restrict__ bias, short* __restrict__ qg,
    short* __restrict__ kgo, short* __restrict__ vtg) {
  constexpr int K = 256;
  __shared__ short tlt[64][130];  // V staging [hd][t-permuted, 128 wide], stride 130
  int wid = threadIdx.x >> 6, lane = threadIdx.x & 63;
  int m0 = blockIdx.x * 128 + wid * 16;   // m-set 0; m-set 1 = m0 + 64
  int n0 = blockIdx.y * 64;
  int row = lane & 15, kg = lane >> 4;
  f32x4 acc[2][4] = {};
  const short* Ap0 = A + (size_t)(m0 + row) * K + kg * 8;
  const short* Ap1 = Ap0 + (size_t)64 * K;
  const short* Bp0 = Bt + (size_t)(n0 + row) * K + kg * 8;
  #pragma unroll
  for (int k = 0; k < K; k += 32) {
    bf16x8 af0 = *(const bf16x8*)(Ap0 + k);
    bf16x8 af1 = *(const bf16x8*)(Ap1 + k);
    #pragma unroll
    for (int nt = 0; nt < 4; nt++) {
      bf16x8 bf = *(const bf16x8*)(Bp0 + (size_t)nt * 16 * K + k);
      acc[0][nt] = __builtin_amdgcn_mfma_f32_16x16x32_bf16(af0, bf, acc[0][nt], 0, 0, 0);
      acc[1][nt] = __builtin_amdgcn_mfma_f32_16x16x32_bf16(af1, bf, acc[1][nt], 0, 0, 0);
    }
  }
  int sec = n0 >> 8, hh = (n0 >> 6) & 3;
  int bB = (blockIdx.x * 128) >> 11, t0 = (blockIdx.x * 128) & (Tx - 1);
  if (sec < 2) {
    #pragma unroll
    for (int ms = 0; ms < 2; ms++)
      #pragma unroll
      for (int nt = 0; nt < 4; nt++)
        #pragma unroll
        for (int r = 0; r < 4; r++) {
          int m = m0 + ms * 64 + kg * 4 + r;
          int n = n0 + nt * 16 + row;
          int b = m >> 11, t = m & (Tx - 1), hd = n & 63;
          float v = acc[ms][nt][r] + bias[n];
          if (sec == 0)
            qg[(((size_t)b * Hx + hh) * Tx + t) * 64 + hd] = f2bf(v * QSCALE);
          else
            kgo[(((size_t)b * Hx + hh) * Tx + t) * 64 + hd] = f2bf(v);
        }
  } else {
    // V: stage sigma-permuted transposed tile (two 64-t chunks), write V^T rows coalesced.
    // within each 64-chunk: tau = wid*16 + kg*4 + r -> p = (wid>>1)*32 + kg*8 + (wid&1)*4 + r
    int tlb = (wid >> 1) * 32 + kg * 8 + (wid & 1) * 4;
    #pragma unroll
    for (int ms = 0; ms < 2; ms++) {
      int tl = ms * 64 + tlb;
      #pragma unroll
      for (int nt = 0; nt < 4; nt++) {
        int n = n0 + nt * 16 + row;
        float bn = bias[n];
        int hd = nt * 16 + row;
        *(unsigned*)&tlt[hd][tl]     = cvtpk(acc[ms][nt][0] + bn, acc[ms][nt][1] + bn);
        *(unsigned*)&tlt[hd][tl + 2] = cvtpk(acc[ms][nt][2] + bn, acc[ms][nt][3] + bn);
      }
    }
    __syncthreads();
    int hd = threadIdx.x >> 2, tch = (threadIdx.x & 3) * 32;
    short* vr = vtg + (((size_t)bB * Hx + hh) * 64 + hd) * Tx + t0 + tch;
    #pragma unroll
    for (int j = 0; j < 32; j += 2) *(unsigned*)(vr + j) = *(unsigned*)&tlt[hd][tch + j];
  }
}

// ---- 5. flash attention, split-KV x4, 4 waves x 32q = 128 q/block, fixed-shift softmax ----
// R9-proven structure; PV B-frags single b128 at K-frag offsets (sigma'd V).
#define KVB 64
__global__ __launch_bounds__(256) void k_attn(const short* __restrict__ qg,
                                              const short* __restrict__ kgl,
                                              const short* __restrict__ vtg,
                                              short* __restrict__ po,
                                              float* __restrict__ ps) {
  // LDS (shorts): K dbuf 2x[64 kv][64 d] @0, V^T dbuf 2x[64 d][64 kv] @8192
  __shared__ short lds[16384];
  const int bid = blockIdx.x;
  const int g = bid & (16 * NSPLIT - 1);
  const int sp = g & (NSPLIT - 1);
  const int bh = g >> ZSHIFT;
  constexpr int kvlen = Tx / NSPLIT;
  const int kvbase = sp * kvlen;
  const int wid = threadIdx.x >> 6, lane = threadIdx.x & 63;
  const int row = lane & 15, kg4 = lane >> 4;
  const int q0 = (bid >> (4 + ZSHIFT)) * 128 + wid * 32;
  const short* qbase = qg + (size_t)bh * Tx * 64;
  const short* kbase = kgl + (size_t)bh * Tx * 64;
  const short* vbase = vtg + (size_t)bh * 64 * Tx;

  bf16x8 qf[2][2];
  #pragma unroll
  for (int qs = 0; qs < 2; ++qs)
    #pragma unroll
    for (int c = 0; c < 2; ++c)
      qf[qs][c] = *(const bf16x8*)(qbase + (size_t)(q0 + qs * 16 + row) * 64 + c * 32 + kg4 * 8);

  // hoisted staging addressing: wave-uniform LDS dest, pre-swizzled global src.
  // LDS[r][slot s] = SRC[r][s ^ (r&7)] (16B slots, 8 per 128B row)
  const int idx0 = wid * 64 + lane, idx1 = idx0 + 256;
  const int rr0 = idx0 >> 3, sl0 = (idx0 & 7) ^ (rr0 & 7);
  const int rr1 = idx1 >> 3, sl1 = (idx1 & 7) ^ (rr1 & 7);
  const short* ks0 = kbase + (size_t)(kvbase + rr0) * 64 + sl0 * 8;
  const short* ks1 = kbase + (size_t)(kvbase + rr1) * 64 + sl1 * 8;
  const short* vs0 = vbase + (size_t)rr0 * Tx + kvbase + sl0 * 8;
  const short* vs1 = vbase + (size_t)rr1 * Tx + kvbase + sl1 * 8;
  short* const kd0 = lds + wid * 512;
  short* const kd1 = lds + wid * 512 + 2048;
  short* const vd0 = lds + 8192 + wid * 512;
  short* const vd1 = lds + 8192 + wid * 512 + 2048;
  auto stage = [&](int sbuf, int itn) {
    const int ko = itn * 4096, vo = itn * 64, so = sbuf * 4096;
    gload16(ks0 + ko, kd0 + so);
    gload16(ks1 + ko, kd1 + so);
    gload16(vs0 + vo, vd0 + so);
    gload16(vs1 + vo, vd1 + so);
  };

  const int swz = row & 7;
  const int kc0 = (kg4 ^ swz) * 8;         // b128 frag offsets, shared by K and sigma'd V
  const int kc1 = ((4 + kg4) ^ swz) * 8;
  int vro[4];
  #pragma unroll
  for (int nt = 0; nt < 4; ++nt) vro[nt] = (nt * 16 + row) * 64;

  float l0 = 0.f, l1 = 0.f;
  f32x4 oa0[4] = {}, oa1[4] = {};
  constexpr int nit = kvlen / KVB;

  stage(0, 0);
  #pragma unroll 2
  for (int it = 0; it < nit; ++it) {
    const int cur = it & 1;
    if (it + 1 < nit) {
      stage(cur ^ 1, it + 1);
      asm volatile("s_waitcnt vmcnt(4)" ::: "memory");
    } else {
      asm volatile("s_waitcnt vmcnt(0)" ::: "memory");
    }
    __builtin_amdgcn_s_barrier();

    const short* Kb = lds + (cur << 12);
    const short* Vb = lds + 8192 + (cur << 12);

    // QK^T (C seeded -SHIFT) -> exp2 -> pack per t-tile; 2 q-sets
    union U { unsigned u[4]; bf16x8 v; };
    U a00, a01, a10, a11;
    float rs0 = 0.f, rs1 = 0.f;
    __builtin_amdgcn_s_setprio(1);
    #pragma unroll
    for (int t = 0; t < 4; ++t) {
      const short* kr = Kb + vro[t];
      bf16x8 kf0 = *(const bf16x8*)(kr + kc0);
      bf16x8 kf1 = *(const bf16x8*)(kr + kc1);
      f32x4 x0 = {-SHIFT, -SHIFT, -SHIFT, -SHIFT};
      f32x4 x1 = {-SHIFT, -SHIFT, -SHIFT, -SHIFT};
      x0 = __builtin_amdgcn_mfma_f32_16x16x32_bf16(kf0, qf[0][0], x0, 0, 0, 0);
      x0 = __builtin_amdgcn_mfma_f32_16x16x32_bf16(kf1, qf[0][1], x0, 0, 0, 0);
      x1 = __builtin_amdgcn_mfma_f32_16x16x32_bf16(kf0, qf[1][0], x1, 0, 0, 0);
      x1 = __builtin_amdgcn_mfma_f32_16x16x32_bf16(kf1, qf[1][1], x1, 0, 0, 0);
      float e0 = fexp2(x0[0]), e1 = fexp2(x0[1]), e2 = fexp2(x0[2]), e3 = fexp2(x0[3]);
      rs0 += (e0 + e1) + (e2 + e3);
      unsigned w0 = cvtpk(e0, e1), w1 = cvtpk(e2, e3);
      float f0 = fexp2(x1[0]), f1 = fexp2(x1[1]), f2 = fexp2(x1[2]), f3 = fexp2(x1[3]);
      rs1 += (f0 + f1) + (f2 + f3);
      unsigned y0 = cvtpk(f0, f1), y1 = cvtpk(f2, f3);
      if (t < 2) {
        a00.u[t * 2] = w0; a00.u[t * 2 + 1] = w1;
        a10.u[t * 2] = y0; a10.u[t * 2 + 1] = y1;
      } else {
        a01.u[(t - 2) * 2] = w0; a01.u[(t - 2) * 2 + 1] = w1;
        a11.u[(t - 2) * 2] = y0; a11.u[(t - 2) * 2 + 1] = y1;
      }
    }
    __builtin_amdgcn_s_setprio(0);
    l0 += rs0; l1 += rs1;

    // O += P V : A-frag k-slot j -> kv = kc*32 + (j>>2)*16 + kg4*4 + (j&3);
    // sigma'd V makes the matching B-frag a single b128 at kc0/kc1.
    __builtin_amdgcn_s_setprio(1);
    #pragma unroll
    for (int nt = 0; nt < 4; ++nt) {
      const short* vr = Vb + vro[nt];
      bf16x8 vf0 = *(const bf16x8*)(vr + kc0);
      bf16x8 vf1 = *(const bf16x8*)(vr + kc1);
      oa0[nt] = __builtin_amdgcn_mfma_f32_16x16x32_bf16(a00.v, vf0, oa0[nt], 0, 0, 0);
      oa1[nt] = __builtin_amdgcn_mfma_f32_16x16x32_bf16(a10.v, vf0, oa1[nt], 0, 0, 0);
      oa0[nt] = __builtin_amdgcn_mfma_f32_16x16x32_bf16(a01.v, vf1, oa0[nt], 0, 0, 0);
      oa1[nt] = __builtin_amdgcn_mfma_f32_16x16x32_bf16(a11.v, vf1, oa1[nt], 0, 0, 0);
    }
    __builtin_amdgcn_s_setprio(0);
    __builtin_amdgcn_s_barrier();
  }

  // epilogue: reduce l across kv-groups once, write partials
  l0 += __shfl_xor(l0, 16, 64); l0 += __shfl_xor(l0, 32, 64);
  l1 += __shfl_xor(l1, 16, 64); l1 += __shfl_xor(l1, 32, 64);
  float li0[4], li1[4];
  #pragma unroll
  for (int r = 0; r < 4; ++r) {
    li0[r] = 1.f / __shfl(l0, kg4 * 4 + r, 64);
    li1[r] = 1.f / __shfl(l1, kg4 * 4 + r, 64);
  }
  short* pob = po + (((size_t)sp * 16 + bh) * Tx) * 64;
  #pragma unroll
  for (int nt = 0; nt < 4; ++nt)
    #pragma unroll
    for (int r = 0; r < 4; ++r) {
      int t = q0 + kg4 * 4 + r;
      pob[(size_t)t * 64 + nt * 16 + row] = f2bf(oa0[nt][r] * li0[r]);
      pob[(size_t)(t + 16) * 64 + nt * 16 + row] = f2bf(oa1[nt][r] * li1[r]);
    }
  if (kg4 == 0) {
    float* psb = ps + ((size_t)sp * 16 + bh) * Tx;
    psb[q0 + row] = SHIFT + __log2f(l0);
    psb[q0 + 16 + row] = SHIFT + __log2f(l1);
  }
}

// ---- 6. fused merge + proj GEMM + bias + residual (no aout round-trip) ----
__global__ __launch_bounds__(256) void k_proj(
    const short* __restrict__ po, const float* __restrict__ ps,
    const short* __restrict__ Bt, const float* __restrict__ bias,
    const float* __restrict__ x, float* __restrict__ out) {
  __shared__ float tlt[128][65];
  const int wid = threadIdx.x >> 6, lane = threadIdx.x & 63;
  const int row = lane & 15, kg = lane >> 4;
  const int mb = blockIdx.x * 64;
  const int b = mb >> 11, t0 = mb & (Tx - 1);
  const int n0 = blockIdx.y * 128;
  const int t = t0 + wid * 16 + row;   // this lane's A-row (time index)

  // per-head LSE merge weights for this t
  float wgt[4][NSPLIT], dinv[4];
  #pragma unroll
  for (int h = 0; h < 4; ++h) {
    float s0[NSPLIT], mx = -1e30f;
    #pragma unroll
    for (int sp = 0; sp < NSPLIT; ++sp) {
      s0[sp] = ps[((size_t)sp * 16 + b * 4 + h) * Tx + t];
      mx = fmaxf(mx, s0[sp]);
    }
    float d = 0.f;
    #pragma unroll
    for (int sp = 0; sp < NSPLIT; ++sp) { wgt[h][sp] = fexp2(s0[sp] - mx); d += wgt[h][sp]; }
    dinv[h] = 1.f / d;
  }

  // accumulate weighted partials into the lane's 64 A-elements
  float a[8][8] = {};
  #pragma unroll
  for (int sp = 0; sp < NSPLIT; ++sp) {
    #pragma unroll
    for (int j = 0; j < 8; ++j) {
      int c = j * 32 + kg * 8;
      int h = c >> 6, d0 = c & 63;
      const short* q = po + (((size_t)sp * 16 + b * 4 + h) * Tx + t) * 64 + d0;
      bf16x8 v = *(const bf16x8*)q;
      float wv = wgt[h][sp];
      #pragma unroll
      for (int e = 0; e < 8; ++e) a[j][e] += wv * bf2f(v[e]);
    }
  }
  // normalize + pack A-frags
  bf16x8 af[8];
  #pragma unroll
  for (int j = 0; j < 8; ++j) {
    float dv = dinv[(j * 32 + kg * 8) >> 6];
    union { unsigned u[4]; bf16x8 v; } p;
    #pragma unroll
    for (int e = 0; e < 4; ++e) p.u[e] = cvtpk(a[j][2 * e] * dv, a[j][2 * e + 1] * dv);
    af[j] = p.v;
  }

  // GEMM: A in regs, B from global (L2-hot 128 KB)
  f32x4 acc[8] = {};
  #pragma unroll
  for (int j = 0; j < 8; ++j) {
    #pragma unroll
    for (int nt = 0; nt < 8; ++nt) {
      bf16x8 bf = *(const bf16x8*)(Bt + (size_t)(n0 + nt * 16 + row) * 256 + j * 32 + kg * 8);
      acc[nt] = __builtin_amdgcn_mfma_f32_16x16x32_bf16(af[j], bf, acc[nt], 0, 0, 0);
    }
  }

  // transposed epilogue with residual
  #pragma unroll
  for (int nt = 0; nt < 8; ++nt) {
    float bn = bias[n0 + nt * 16 + row];
    #pragma unroll
    for (int r = 0; r < 4; ++r)
      tlt[nt * 16 + row][wid * 16 + kg * 4 + r] = acc[nt][r] + bn;
  }
  __syncthreads();
  int cl = threadIdx.x >> 1, tch = (threadIdx.x & 1) * 32;
  int c = n0 + cl;
  const float* xr = x + ((size_t)b * Cx + c) * Tx + t0 + tch;
  float* orow = out + ((size_t)b * Cx + c) * Tx + t0 + tch;
  #pragma unroll
  for (int j = 0; j < 32; j += 4) {
    f32x4 xv = *(const f32x4*)(xr + j);
    f32x4 v;
    #pragma unroll
    for (int jj = 0; jj < 4; ++jj) v[jj] = xv[jj] + tlt[cl][tch + j + jj];
    *(f32x4*)(orow + j) = v;
  }
}

extern "C" void kernel_launch(void* const* d_in, const int* in_sizes, int n_in,
                              void* d_out, int out_size, void* d_ws, size_t ws_size,
                              hipStream_t stream) {
  const float* x     = (const float*)d_in[0];
  const float* gn_w  = (const float*)d_in[1];
  const float* gn_b  = (const float*)d_in[2];
  const float* w_qkv = (const float*)d_in[3];
  const float* b_qkv = (const float*)d_in[4];
  const float* w_out = (const float*)d_in[5];
  const float* b_out = (const float*)d_in[6];
  float* out = (float*)d_out;

  char* ws = (char*)d_ws;
  size_t off = 0;
  auto alloc = [&](size_t bytes) -> void* {
    void* p = ws + off;
    off += bytes;
    off = (off + 255) & ~(size_t)255;
    return p;
  };
  float2* part  = (float2*)alloc((size_t)Bx * Gx * 8 * sizeof(float2));
  short* h      = (short*)alloc((size_t)Bx * Tx * Cx * 2);
  short* wqkvb  = (short*)alloc((size_t)3 * Cx * Cx * 2);
  short* woutb  = (short*)alloc((size_t)Cx * Cx * 2);
  short* qg     = (short*)alloc((size_t)Bx * Hx * Tx * 64 * 2);
  short* kgo    = (short*)alloc((size_t)Bx * Hx * Tx * 64 * 2);
  short* vtg    = (short*)alloc((size_t)Bx * Hx * 64 * Tx * 2);
  short* po     = (short*)alloc((size_t)NSPLIT * 16 * Tx * 64 * 2);
  float* ps     = (float*)alloc((size_t)NSPLIT * 16 * Tx * sizeof(float));

  k_pre<<<Bx * Gx * 8 + (Cx * Cx + NTHREADS - 1) / NTHREADS, NTHREADS, 0, stream>>>(
      x, part, w_qkv, w_out, wqkvb, woutb);
  k_gn_apply<<<dim3(Tx / 128, Cx / 32, Bx), NTHREADS, 0, stream>>>(x, gn_w, gn_b, part, h);
  k_gemm_qkv<<<dim3(Bx * Tx / 128, 3 * Cx / 64), NTHREADS, 0, stream>>>(h, wqkvb, b_qkv, qg, kgo, vtg);
  k_attn<<<16 * 16 * NSPLIT, 256, 0, stream>>>(qg, kgo, vtg, po, ps);
  k_proj<<<dim3(Bx * Tx / 64, 2), NTHREADS, 0, stream>>>(po, ps, woutb, b_out, x, out);
}